// Round 13
// baseline (754.946 us; speedup 1.0000x reference)
//
#include <hip/hip_runtime.h>

#define N_NODES 100000
#define N_EDGES 1600000
#define F_IN 128
#define HID 64
#define NLAYERS 4
#define N_GRAPHS 512
#define N_CLASSES 10
#define N_TILES ((N_NODES + 255) / 256)   // 391
#define AGG_BLOCKS 2048

typedef unsigned int uint_t;
typedef unsigned short ushort_t;

__device__ __forceinline__ float lo_bf(uint_t w) { return __uint_as_float(w << 16); }
__device__ __forceinline__ float hi_bf(uint_t w) { return __uint_as_float(w & 0xffff0000u); }
__device__ __forceinline__ ushort_t f2bf(float f) {
    uint_t u = __float_as_uint(f);
    u += 0x7fffu + ((u >> 16) & 1u);   // round-to-nearest-even
    return (ushort_t)(u >> 16);
}
__device__ __forceinline__ uint_t pack2(float a, float b) {
    return ((uint_t)f2bf(b) << 16) | (uint_t)f2bf(a);
}

// ---------------- workspace zeroing ----------------
__global__ __launch_bounds__(256) void k_zero(int* __restrict__ deg,
                                              float* __restrict__ statsA,
                                              float* __restrict__ pooled) {
    int i = blockIdx.x * 256 + threadIdx.x;
    if (i < N_NODES) deg[i] = 0;
    if (i < NLAYERS * 128) statsA[i] = 0.f;
    if (i < N_GRAPHS * 256) pooled[i] = 0.f;
}

// ---------------- CSR build ----------------
__global__ __launch_bounds__(256) void k_degree_rank(const int* __restrict__ dst,
                                                     int* __restrict__ deg,
                                                     ushort_t* __restrict__ rank) {
    int base = blockIdx.x * 1024 + threadIdx.x;
    #pragma unroll
    for (int j = 0; j < 4; ++j) {
        int e = base + j * 256;
        if (e < N_EDGES) {
            int d = dst[e];
            int r = 0;
            if ((uint_t)d < (uint_t)N_NODES) r = atomicAdd(&deg[d], 1);
            rank[e] = (ushort_t)r;
        }
    }
}

__global__ __launch_bounds__(256) void k_tilesum(const int* __restrict__ deg, int* __restrict__ bsum) {
    __shared__ int sh[256];
    int tid = threadIdx.x;
    int i = blockIdx.x * 256 + tid;
    sh[tid] = (i < N_NODES) ? deg[i] : 0;
    __syncthreads();
    for (int off = 128; off > 0; off >>= 1) {
        if (tid < off) sh[tid] += sh[tid + off];
        __syncthreads();
    }
    if (tid == 0) bsum[blockIdx.x] = sh[0];
}

__global__ __launch_bounds__(512) void k_tilescan(const int* __restrict__ bsum, int* __restrict__ boff) {
    __shared__ int sh[512];
    int tid = threadIdx.x;
    sh[tid] = (tid < N_TILES) ? bsum[tid] : 0;
    __syncthreads();
    for (int off = 1; off < 512; off <<= 1) {
        int t = (tid >= off) ? sh[tid - off] : 0;
        __syncthreads();
        sh[tid] += t;
        __syncthreads();
    }
    if (tid < N_TILES) boff[tid + 1] = sh[tid];
    if (tid == 0) boff[0] = 0;
}

__global__ __launch_bounds__(256) void k_tileapply(const int* __restrict__ deg, const int* __restrict__ boff,
                                                   int* __restrict__ row_ptr) {
    __shared__ int sh[256];
    int tid = threadIdx.x, b = blockIdx.x;
    int i = b * 256 + tid;
    sh[tid] = (i < N_NODES) ? deg[i] : 0;
    __syncthreads();
    for (int off = 1; off < 256; off <<= 1) {
        int t = (tid >= off) ? sh[tid - off] : 0;
        __syncthreads();
        sh[tid] += t;
        __syncthreads();
    }
    if (i < N_NODES) row_ptr[i + 1] = boff[b] + sh[tid];
    if (i == 0) row_ptr[0] = 0;
}

__global__ __launch_bounds__(256) void k_fill(const int* __restrict__ src, const int* __restrict__ dst,
                                              const ushort_t* __restrict__ rank, const int* __restrict__ row_ptr,
                                              int* __restrict__ col_src) {
    int base = blockIdx.x * 1024 + threadIdx.x;
    #pragma unroll
    for (int j = 0; j < 4; ++j) {
        int e = base + j * 256;
        if (e < N_EDGES) {
            int d = dst[e];
            if ((uint_t)d >= (uint_t)N_NODES) continue;
            int pos = row_ptr[d] + (int)rank[e];
            uint_t s = (uint_t)src[e];
            if (s >= (uint_t)N_NODES) s = 0;
            if ((uint_t)pos < (uint_t)N_EDGES) col_src[pos] = (int)s;
        }
    }
}

// ---------------- aggregation on bf16 y -> bf16 u, with fused column stats ----------------
// Grid-strided (AGG_BLOCKS blocks); each block accumulates sum/sumsq locally and
// issues 128 atomics at the end.
__global__ __launch_bounds__(256) void k_aggregate_u(const uint2* __restrict__ y2,
                                                     const int* __restrict__ row_ptr,
                                                     const int* __restrict__ col_src,
                                                     const float* __restrict__ eps, int layer,
                                                     const float* __restrict__ b1,
                                                     uint2* __restrict__ u2,
                                                     float* __restrict__ sums) {
    __shared__ float Sl[4][16][8];
    int wid = threadIdx.x >> 6, lane = threadIdx.x & 63;
    int gid = lane >> 4, l4 = lane & 15;
    float one_eps = 1.0f + eps[layer];

    float st[4] = {0.f, 0.f, 0.f, 0.f}, sq[4] = {0.f, 0.f, 0.f, 0.f};

    for (int nb = blockIdx.x * 4; nb < N_NODES; nb += AGG_BLOCKS * 4) {
        int node = nb + wid;
        if (node < N_NODES) {
            int e0 = row_ptr[node], e1 = row_ptr[node + 1];
            if (e0 < 0) e0 = 0;
            if (e1 > N_EDGES) e1 = N_EDGES;
            if (e1 < e0) e1 = e0;
            int len = e1 - e0;
            int main_end = e0 + (len & ~15);

            float4 acc[4];
            #pragma unroll
            for (int j = 0; j < 4; ++j) acc[j] = (float4){0.f, 0.f, 0.f, 0.f};

            for (int eb = e0; eb < main_end; eb += 16) {
                #pragma unroll
                for (int j = 0; j < 4; ++j) {
                    uint_t s = min((uint_t)col_src[eb + 4 * j + gid], (uint_t)(N_NODES - 1));
                    uint2 w = y2[(size_t)s * 16 + l4];
                    acc[j].x += lo_bf(w.x); acc[j].y += hi_bf(w.x);
                    acc[j].z += lo_bf(w.y); acc[j].w += hi_bf(w.y);
                }
            }
            #pragma unroll
            for (int j = 0; j < 4; ++j) {
                int ee = main_end + 4 * j + gid;
                if (ee < e1) {
                    uint_t s = min((uint_t)col_src[ee], (uint_t)(N_NODES - 1));
                    uint2 w = y2[(size_t)s * 16 + l4];
                    acc[j].x += lo_bf(w.x); acc[j].y += hi_bf(w.x);
                    acc[j].z += lo_bf(w.y); acc[j].w += hi_bf(w.y);
                }
            }

            float4 t;
            t.x = (acc[0].x + acc[1].x) + (acc[2].x + acc[3].x);
            t.y = (acc[0].y + acc[1].y) + (acc[2].y + acc[3].y);
            t.z = (acc[0].z + acc[1].z) + (acc[2].z + acc[3].z);
            t.w = (acc[0].w + acc[1].w) + (acc[2].w + acc[3].w);
            t.x += __shfl_xor(t.x, 16, 64); t.x += __shfl_xor(t.x, 32, 64);
            t.y += __shfl_xor(t.y, 16, 64); t.y += __shfl_xor(t.y, 32, 64);
            t.z += __shfl_xor(t.z, 16, 64); t.z += __shfl_xor(t.z, 32, 64);
            t.w += __shfl_xor(t.w, 16, 64); t.w += __shfl_xor(t.w, 32, 64);

            if (gid == 0) {
                uint2 ws = y2[(size_t)node * 16 + l4];
                float4 bb = *(const float4*)&b1[4 * l4];
                float ox = t.x + one_eps * lo_bf(ws.x) + bb.x;
                float oy = t.y + one_eps * hi_bf(ws.x) + bb.y;
                float oz = t.z + one_eps * lo_bf(ws.y) + bb.z;
                float ow = t.w + one_eps * hi_bf(ws.y) + bb.w;
                uint2 o2;
                o2.x = pack2(ox, oy);
                o2.y = pack2(oz, ow);
                u2[(size_t)node * 16 + l4] = o2;
                st[0] += ox; sq[0] += ox * ox;
                st[1] += oy; sq[1] += oy * oy;
                st[2] += oz; sq[2] += oz * oz;
                st[3] += ow; sq[3] += ow * ow;
            }
        }
    }

    if (gid == 0) {
        #pragma unroll
        for (int j = 0; j < 4; ++j) { Sl[wid][l4][j] = st[j]; Sl[wid][l4][4 + j] = sq[j]; }
    }
    __syncthreads();
    int tid = threadIdx.x;
    if (tid < 64) {
        int l4c = tid >> 2, o = tid & 3;       // col = 4*l4c + o = tid
        float s  = (Sl[0][l4c][o] + Sl[1][l4c][o]) + (Sl[2][l4c][o] + Sl[3][l4c][o]);
        float ss = (Sl[0][l4c][4 + o] + Sl[1][l4c][4 + o]) + (Sl[2][l4c][4 + o] + Sl[3][l4c][4 + o]);
        atomicAdd(&sums[tid], s);
        atomicAdd(&sums[64 + tid], ss);
    }
}

// ---------------- GEMM1 (layer 0 only): ybf = bf16(x @ W1_0) ----------------
template <int K>
__global__ __launch_bounds__(256) void k_gemm1(const float* __restrict__ A,
                                               const float* __restrict__ W,
                                               ushort_t* __restrict__ out) {
    constexpr int KP = K + 4;
    constexpr int KQ = K / 4;
    __shared__ float Al[64 * KP];
    __shared__ float Wl[K * 64];
    int tid = threadIdx.x;
    int base = blockIdx.x * 64;

    for (int i = tid; i < K * 16; i += 256)
        ((float4*)Wl)[i] = ((const float4*)W)[i];

    if (base + 64 <= N_NODES) {
        const float4* Ag = (const float4*)(A + (size_t)base * K);
        for (int i = tid; i < 16 * K; i += 256) {
            int row = i / KQ, kk = (i % KQ) * 4;
            float4 v = Ag[i];
            *(float4*)&Al[row * KP + kk] = v;
        }
    } else {
        for (int i = tid; i < 16 * K; i += 256) {
            int row = i / KQ, kk = (i % KQ) * 4;
            int grow = base + row; if (grow >= N_NODES) grow = N_NODES - 1;
            float4 v = ((const float4*)(A + (size_t)grow * K))[i % KQ];
            *(float4*)&Al[row * KP + kk] = v;
        }
    }
    __syncthreads();

    int ct = (tid & 15) * 4;
    int rb = (tid >> 4) * 4;
    float4 acc0 = {0.f, 0.f, 0.f, 0.f}, acc1 = acc0, acc2 = acc0, acc3 = acc0;
    const float* A0 = &Al[(rb + 0) * KP];
    const float* A1 = &Al[(rb + 1) * KP];
    const float* A2 = &Al[(rb + 2) * KP];
    const float* A3 = &Al[(rb + 3) * KP];
    #pragma unroll 4
    for (int k = 0; k < K; ++k) {
        float4 w = *(const float4*)&Wl[k * 64 + ct];
        float a0 = A0[k], a1 = A1[k], a2 = A2[k], a3 = A3[k];
        acc0.x = fmaf(a0, w.x, acc0.x); acc0.y = fmaf(a0, w.y, acc0.y);
        acc0.z = fmaf(a0, w.z, acc0.z); acc0.w = fmaf(a0, w.w, acc0.w);
        acc1.x = fmaf(a1, w.x, acc1.x); acc1.y = fmaf(a1, w.y, acc1.y);
        acc1.z = fmaf(a1, w.z, acc1.z); acc1.w = fmaf(a1, w.w, acc1.w);
        acc2.x = fmaf(a2, w.x, acc2.x); acc2.y = fmaf(a2, w.y, acc2.y);
        acc2.z = fmaf(a2, w.z, acc2.z); acc2.w = fmaf(a2, w.w, acc2.w);
        acc3.x = fmaf(a3, w.x, acc3.x); acc3.y = fmaf(a3, w.y, acc3.y);
        acc3.z = fmaf(a3, w.z, acc3.z); acc3.w = fmaf(a3, w.w, acc3.w);
    }

    float4 accs[4] = {acc0, acc1, acc2, acc3};
    #pragma unroll
    for (int r = 0; r < 4; ++r) {
        int row = base + rb + r;
        if (row < N_NODES) {
            ushort4 o;
            o.x = f2bf(accs[r].x); o.y = f2bf(accs[r].y);
            o.z = f2bf(accs[r].z); o.w = f2bf(accs[r].w);
            *(ushort4*)&out[(size_t)row * 64 + ct] = o;
        }
    }
}

// ---------------- fused layer tail (bf16 u input) ----------------
template <bool NEXT>
__global__ __launch_bounds__(256) void k_fused(const uint2* __restrict__ U2,
                                               const float* __restrict__ W2,
                                               const float* __restrict__ sums,
                                               const float* __restrict__ g_,
                                               const float* __restrict__ be,
                                               const float* __restrict__ b2,
                                               const int* __restrict__ batch,
                                               float* __restrict__ pooled, int layer,
                                               const float* __restrict__ W1n,
                                               ushort_t* __restrict__ ynext) {
    constexpr int K = 64, KP = 68, KQ = 16;
    __shared__ float Al[64 * KP];
    __shared__ float Wl[K * 64];
    __shared__ float W1l[NEXT ? K * 64 : 4];
    __shared__ float Pl[256];
    __shared__ __align__(16) float Sc[64];
    __shared__ __align__(16) float Sh[64];
    int tid = threadIdx.x;
    int base = blockIdx.x * 64;

    if (tid < 64) {
        const float inv_n = 1.0f / N_NODES;
        float mean = sums[tid] * inv_n;
        float var = sums[64 + tid] * inv_n - mean * mean;
        if (var < 0.f) var = 0.f;
        float inv = rsqrtf(var + 1e-5f);
        float sc = inv * g_[tid];
        Sc[tid] = sc;
        Sh[tid] = be[tid] - mean * sc;
    }
    for (int i = tid; i < K * 16; i += 256)
        ((float4*)Wl)[i] = ((const float4*)W2)[i];
    if (NEXT) {
        for (int i = tid; i < K * 16; i += 256)
            ((float4*)W1l)[i] = ((const float4*)W1n)[i];
    }
    __syncthreads();

    {
        bool full = (base + 64 <= N_NODES);
        for (int i = tid; i < 16 * K; i += 256) {
            int row = i / KQ, kq = i % KQ, kk = kq * 4;
            int grow = base + row;
            if (!full && grow >= N_NODES) grow = N_NODES - 1;
            uint2 w = U2[(size_t)grow * 16 + kq];
            float4 v = {lo_bf(w.x), hi_bf(w.x), lo_bf(w.y), hi_bf(w.y)};
            float4 sc = *(const float4*)&Sc[kk];
            float4 sh = *(const float4*)&Sh[kk];
            v.x = fmaxf(fmaf(v.x, sc.x, sh.x), 0.f);
            v.y = fmaxf(fmaf(v.y, sc.y, sh.y), 0.f);
            v.z = fmaxf(fmaf(v.z, sc.z, sh.z), 0.f);
            v.w = fmaxf(fmaf(v.w, sc.w, sh.w), 0.f);
            *(float4*)&Al[row * KP + kk] = v;
        }
    }
    __syncthreads();

    int ct = (tid & 15) * 4;
    int rb = (tid >> 4) * 4;
    float4 acc0 = {0.f, 0.f, 0.f, 0.f}, acc1 = acc0, acc2 = acc0, acc3 = acc0;
    {
        const float* A0 = &Al[(rb + 0) * KP];
        const float* A1 = &Al[(rb + 1) * KP];
        const float* A2 = &Al[(rb + 2) * KP];
        const float* A3 = &Al[(rb + 3) * KP];
        #pragma unroll 4
        for (int k = 0; k < K; ++k) {
            float4 w = *(const float4*)&Wl[k * 64 + ct];
            float a0 = A0[k], a1 = A1[k], a2 = A2[k], a3 = A3[k];
            acc0.x = fmaf(a0, w.x, acc0.x); acc0.y = fmaf(a0, w.y, acc0.y);
            acc0.z = fmaf(a0, w.z, acc0.z); acc0.w = fmaf(a0, w.w, acc0.w);
            acc1.x = fmaf(a1, w.x, acc1.x); acc1.y = fmaf(a1, w.y, acc1.y);
            acc1.z = fmaf(a1, w.z, acc1.z); acc1.w = fmaf(a1, w.w, acc1.w);
            acc2.x = fmaf(a2, w.x, acc2.x); acc2.y = fmaf(a2, w.y, acc2.y);
            acc2.z = fmaf(a2, w.z, acc2.z); acc2.w = fmaf(a2, w.w, acc2.w);
            acc3.x = fmaf(a3, w.x, acc3.x); acc3.y = fmaf(a3, w.y, acc3.y);
            acc3.z = fmaf(a3, w.z, acc3.z); acc3.w = fmaf(a3, w.w, acc3.w);
        }
    }
    __syncthreads();   // done reading Al (u); reuse it for h

    {
        float4 bb = *(const float4*)&b2[ct];
        float4 accs[4] = {acc0, acc1, acc2, acc3};
        #pragma unroll
        for (int r = 0; r < 4; ++r) {
            float4 o;
            o.x = fmaxf(accs[r].x + bb.x, 0.f);
            o.y = fmaxf(accs[r].y + bb.y, 0.f);
            o.z = fmaxf(accs[r].z + bb.z, 0.f);
            o.w = fmaxf(accs[r].w + bb.w, 0.f);
            *(float4*)&Al[(rb + r) * KP + ct] = o;
        }
    }
    __syncthreads();   // h tile ready in Al

    // ---- pooling over graph segments (batch sorted) ----
    {
        int lastEx = base + 64; if (lastEx > N_NODES) lastEx = N_NODES;
        int gstart = batch[base];
        int gend = batch[lastEx - 1];
        if (gstart < 0) gstart = 0;
        if (gend > N_GRAPHS - 1) gend = N_GRAPHS - 1;
        int col = tid & 63, q = tid >> 6;
        int rs = base;
        for (int g = gstart; g <= gend; ++g) {
            int lo = rs, hi = lastEx;
            while (lo < hi) { int mid = (lo + hi) >> 1; if (batch[mid] <= g) lo = mid + 1; else hi = mid; }
            int re = lo;
            float s = 0.f;
            for (int r = rs + q; r < re; r += 4) s += Al[(r - base) * KP + col];
            Pl[tid] = s;
            __syncthreads();
            if (tid < 64) {
                float tot = (Pl[col] + Pl[64 + col]) + (Pl[128 + col] + Pl[192 + col]);
                atomicAdd(&pooled[g * 256 + layer * 64 + col], tot);
            }
            __syncthreads();
            rs = re;
        }
    }

    // ---- second GEMM: ynext = bf16( h @ W1n ) ----
    if (NEXT) {
        float4 y0 = {0.f, 0.f, 0.f, 0.f}, y1 = y0, y2_ = y0, y3 = y0;
        const float* A0 = &Al[(rb + 0) * KP];
        const float* A1 = &Al[(rb + 1) * KP];
        const float* A2 = &Al[(rb + 2) * KP];
        const float* A3 = &Al[(rb + 3) * KP];
        #pragma unroll 4
        for (int k = 0; k < K; ++k) {
            float4 w = *(const float4*)&W1l[k * 64 + ct];
            float a0 = A0[k], a1 = A1[k], a2 = A2[k], a3 = A3[k];
            y0.x = fmaf(a0, w.x, y0.x); y0.y = fmaf(a0, w.y, y0.y);
            y0.z = fmaf(a0, w.z, y0.z); y0.w = fmaf(a0, w.w, y0.w);
            y1.x = fmaf(a1, w.x, y1.x); y1.y = fmaf(a1, w.y, y1.y);
            y1.z = fmaf(a1, w.z, y1.z); y1.w = fmaf(a1, w.w, y1.w);
            y2_.x = fmaf(a2, w.x, y2_.x); y2_.y = fmaf(a2, w.y, y2_.y);
            y2_.z = fmaf(a2, w.z, y2_.z); y2_.w = fmaf(a2, w.w, y2_.w);
            y3.x = fmaf(a3, w.x, y3.x); y3.y = fmaf(a3, w.y, y3.y);
            y3.z = fmaf(a3, w.z, y3.z); y3.w = fmaf(a3, w.w, y3.w);
        }
        float4 ys[4] = {y0, y1, y2_, y3};
        #pragma unroll
        for (int r = 0; r < 4; ++r) {
            int row = base + rb + r;
            if (row < N_NODES) {
                ushort4 o;
                o.x = f2bf(ys[r].x); o.y = f2bf(ys[r].y);
                o.z = f2bf(ys[r].z); o.w = f2bf(ys[r].w);
                *(ushort4*)&ynext[(size_t)row * 64 + ct] = o;
            }
        }
    }
}

// ---------------- head ----------------
__global__ __launch_bounds__(64) void k_head1(const float* __restrict__ pooled,
                                              const float* __restrict__ W, const float* __restrict__ b,
                                              float* __restrict__ t1) {
    __shared__ __align__(16) float pl[256];
    int g = blockIdx.x, lane = threadIdx.x;
    ((float4*)pl)[lane] = ((const float4*)(pooled + g * 256))[lane];
    __syncthreads();
    float acc = b[lane];
    for (int k = 0; k < 256; ++k) acc += pl[k] * W[k * 64 + lane];
    t1[g * 64 + lane] = acc;
}

__global__ __launch_bounds__(64) void k_head3(const float* __restrict__ t1,
                                              const float* __restrict__ g_, const float* __restrict__ b_,
                                              const float* __restrict__ W2, const float* __restrict__ b2,
                                              float* __restrict__ out) {
    __shared__ float v[64];
    __shared__ float o[16];
    int g = blockIdx.x, lane = threadIdx.x;
    float s = 0.f, q = 0.f;
    for (int r = 0; r < N_GRAPHS; ++r) {
        float vv = t1[r * 64 + lane];
        s += vv; q += vv * vv;
    }
    float mean = s * (1.0f / N_GRAPHS);
    float var = q * (1.0f / N_GRAPHS) - mean * mean;
    if (var < 0.f) var = 0.f;
    float inv = rsqrtf(var + 1e-5f);
    float sc = inv * g_[lane];
    float sh = b_[lane] - mean * sc;
    float x = t1[g * 64 + lane] * sc + sh;
    v[lane] = fmaxf(x, 0.f);
    __syncthreads();
    if (lane < N_CLASSES) {
        float acc = b2[lane];
        for (int k = 0; k < 64; ++k) acc += v[k] * W2[k * N_CLASSES + lane];
        o[lane] = acc;
    }
    __syncthreads();
    if (lane < N_CLASSES) {
        float m = -1e30f;
        for (int k = 0; k < N_CLASSES; ++k) m = fmaxf(m, o[k]);
        float ssum = 0.f;
        for (int k = 0; k < N_CLASSES; ++k) ssum += expf(o[k] - m);
        out[g * N_CLASSES + lane] = o[lane] - m - logf(ssum);
    }
}

// ---------------- launch ----------------
extern "C" void kernel_launch(void* const* d_in, const int* in_sizes, int n_in,
                              void* d_out, int out_size, void* d_ws, size_t ws_size,
                              hipStream_t stream) {
    const float* x      = (const float*)d_in[0];
    const int*   ei     = (const int*)d_in[1];
    const int*   srcArr = ei;
    const int*   dstArr = ei + N_EDGES;
    const int*   batch  = (const int*)d_in[2];
    const float* eps    = (const float*)d_in[3];
    const float* W1_0   = (const float*)d_in[4];
    const float* b1_0   = (const float*)d_in[5];
    const float* g_0    = (const float*)d_in[6];
    const float* be_0   = (const float*)d_in[7];
    const float* W2_0   = (const float*)d_in[8];
    const float* b2_0   = (const float*)d_in[9];
    const float* W1_r   = (const float*)d_in[10];
    const float* b1_r   = (const float*)d_in[11];
    const float* g_r    = (const float*)d_in[12];
    const float* be_r   = (const float*)d_in[13];
    const float* W2_r   = (const float*)d_in[14];
    const float* b2_r   = (const float*)d_in[15];
    const float* lin1W  = (const float*)d_in[16];
    const float* lin1b  = (const float*)d_in[17];
    const float* bn_g   = (const float*)d_in[18];
    const float* bn_b   = (const float*)d_in[19];
    const float* lin2W  = (const float*)d_in[20];
    const float* lin2b  = (const float*)d_in[21];

    char* ws = (char*)d_ws;
    auto alloc = [&](size_t bytes) {
        char* p = ws;
        ws += (bytes + 255) & ~(size_t)255;
        return p;
    };
    int*      deg     = (int*)alloc((size_t)N_NODES * 4);
    int*      row_ptr = (int*)alloc(((size_t)N_NODES + 1) * 4);
    ushort_t* rank    = (ushort_t*)alloc((size_t)N_EDGES * 2);
    int*      bsum    = (int*)alloc((size_t)N_TILES * 4);
    int*      boff    = (int*)alloc(((size_t)N_TILES + 1) * 4);
    int*      col_src = (int*)alloc((size_t)N_EDGES * 4);
    ushort_t* ybf     = (ushort_t*)alloc((size_t)N_NODES * 64 * 2);
    ushort_t* ubf     = (ushort_t*)alloc((size_t)N_NODES * 64 * 2);
    float*    statsA  = (float*)alloc(NLAYERS * 128 * 4);
    float*    pooled  = (float*)alloc((size_t)N_GRAPHS * 256 * 4);
    float*    t1      = (float*)alloc((size_t)N_GRAPHS * 64 * 4);

    const int e4_grid = (N_EDGES + 1023) / 1024;
    k_zero<<<(N_GRAPHS * 256 + 255) / 256, 256, 0, stream>>>(deg, statsA, pooled);
    k_degree_rank<<<e4_grid, 256, 0, stream>>>(dstArr, deg, rank);
    k_tilesum<<<N_TILES, 256, 0, stream>>>(deg, bsum);
    k_tilescan<<<1, 512, 0, stream>>>(bsum, boff);
    k_tileapply<<<N_TILES, 256, 0, stream>>>(deg, boff, row_ptr);
    k_fill<<<e4_grid, 256, 0, stream>>>(srcArr, dstArr, rank, row_ptr, col_src);

    const int gemm_grid = (N_NODES + 63) / 64;      // 1563

    // layer 0 front GEMM: y0 = bf16(x @ W1_0)
    k_gemm1<128><<<gemm_grid, 256, 0, stream>>>(x, W1_0, ybf);

    for (int l = 0; l < NLAYERS; ++l) {
        const float *b1, *gg, *be, *W2, *b2;
        if (l == 0) { b1 = b1_0; gg = g_0; be = be_0; W2 = W2_0; b2 = b2_0; }
        else {
            b1 = b1_r + (size_t)(l - 1) * 64;
            gg = g_r  + (size_t)(l - 1) * 64;
            be = be_r + (size_t)(l - 1) * 64;
            W2 = W2_r + (size_t)(l - 1) * 64 * 64;
            b2 = b2_r + (size_t)(l - 1) * 64;
        }
        k_aggregate_u<<<AGG_BLOCKS, 256, 0, stream>>>((const uint2*)ybf, row_ptr, col_src, eps, l, b1,
                                                      (uint2*)ubf, statsA + l * 128);
        if (l < NLAYERS - 1) {
            const float* W1n = W1_r + (size_t)l * 64 * 64;
            k_fused<true><<<gemm_grid, 256, 0, stream>>>((const uint2*)ubf, W2, statsA + l * 128, gg, be, b2,
                                                         batch, pooled, l, W1n, ybf);
        } else {
            k_fused<false><<<gemm_grid, 256, 0, stream>>>((const uint2*)ubf, W2, statsA + l * 128, gg, be, b2,
                                                          batch, pooled, l, nullptr, nullptr);
        }
    }

    k_head1<<<N_GRAPHS, 64, 0, stream>>>(pooled, lin1W, lin1b, t1);
    k_head3<<<N_GRAPHS, 64, 0, stream>>>(t1, bn_g, bn_b, lin2W, lin2b, (float*)d_out);
}

// Round 14
// 669.946 us; speedup vs baseline: 1.1269x; 1.1269x over previous
//
#include <hip/hip_runtime.h>

#define N_NODES 100000
#define N_EDGES 1600000
#define F_IN 128
#define HID 64
#define NLAYERS 4
#define N_GRAPHS 512
#define N_CLASSES 10
#define N_TILES ((N_NODES + 255) / 256)   // 391

typedef unsigned int uint_t;
typedef unsigned short ushort_t;

__device__ __forceinline__ float lo_bf(uint_t w) { return __uint_as_float(w << 16); }
__device__ __forceinline__ float hi_bf(uint_t w) { return __uint_as_float(w & 0xffff0000u); }
__device__ __forceinline__ ushort_t f2bf(float f) {
    uint_t u = __float_as_uint(f);
    u += 0x7fffu + ((u >> 16) & 1u);   // round-to-nearest-even
    return (ushort_t)(u >> 16);
}
__device__ __forceinline__ uint_t pack2(float a, float b) {
    return ((uint_t)f2bf(b) << 16) | (uint_t)f2bf(a);
}

// ---------------- workspace zeroing ----------------
__global__ __launch_bounds__(256) void k_zero(int* __restrict__ deg,
                                              float* __restrict__ statsA,
                                              float* __restrict__ pooled) {
    int i = blockIdx.x * 256 + threadIdx.x;
    if (i < N_NODES) deg[i] = 0;
    if (i < NLAYERS * 128) statsA[i] = 0.f;
    if (i < N_GRAPHS * 256) pooled[i] = 0.f;
}

// ---------------- CSR build ----------------
__global__ __launch_bounds__(256) void k_degree_rank(const int* __restrict__ dst,
                                                     int* __restrict__ deg,
                                                     ushort_t* __restrict__ rank) {
    int base = blockIdx.x * 1024 + threadIdx.x;
    #pragma unroll
    for (int j = 0; j < 4; ++j) {
        int e = base + j * 256;
        if (e < N_EDGES) {
            int d = dst[e];
            int r = 0;
            if ((uint_t)d < (uint_t)N_NODES) r = atomicAdd(&deg[d], 1);
            rank[e] = (ushort_t)r;
        }
    }
}

__global__ __launch_bounds__(256) void k_tilesum(const int* __restrict__ deg, int* __restrict__ bsum) {
    __shared__ int sh[256];
    int tid = threadIdx.x;
    int i = blockIdx.x * 256 + tid;
    sh[tid] = (i < N_NODES) ? deg[i] : 0;
    __syncthreads();
    for (int off = 128; off > 0; off >>= 1) {
        if (tid < off) sh[tid] += sh[tid + off];
        __syncthreads();
    }
    if (tid == 0) bsum[blockIdx.x] = sh[0];
}

__global__ __launch_bounds__(512) void k_tilescan(const int* __restrict__ bsum, int* __restrict__ boff) {
    __shared__ int sh[512];
    int tid = threadIdx.x;
    sh[tid] = (tid < N_TILES) ? bsum[tid] : 0;
    __syncthreads();
    for (int off = 1; off < 512; off <<= 1) {
        int t = (tid >= off) ? sh[tid - off] : 0;
        __syncthreads();
        sh[tid] += t;
        __syncthreads();
    }
    if (tid < N_TILES) boff[tid + 1] = sh[tid];
    if (tid == 0) boff[0] = 0;
}

__global__ __launch_bounds__(256) void k_tileapply(const int* __restrict__ deg, const int* __restrict__ boff,
                                                   int* __restrict__ row_ptr) {
    __shared__ int sh[256];
    int tid = threadIdx.x, b = blockIdx.x;
    int i = b * 256 + tid;
    sh[tid] = (i < N_NODES) ? deg[i] : 0;
    __syncthreads();
    for (int off = 1; off < 256; off <<= 1) {
        int t = (tid >= off) ? sh[tid - off] : 0;
        __syncthreads();
        sh[tid] += t;
        __syncthreads();
    }
    if (i < N_NODES) row_ptr[i + 1] = boff[b] + sh[tid];
    if (i == 0) row_ptr[0] = 0;
}

__global__ __launch_bounds__(256) void k_fill(const int* __restrict__ src, const int* __restrict__ dst,
                                              const ushort_t* __restrict__ rank, const int* __restrict__ row_ptr,
                                              int* __restrict__ col_src) {
    int base = blockIdx.x * 1024 + threadIdx.x;
    #pragma unroll
    for (int j = 0; j < 4; ++j) {
        int e = base + j * 256;
        if (e < N_EDGES) {
            int d = dst[e];
            if ((uint_t)d >= (uint_t)N_NODES) continue;
            int pos = row_ptr[d] + (int)rank[e];
            uint_t s = (uint_t)src[e];
            if (s >= (uint_t)N_NODES) s = 0;
            if ((uint_t)pos < (uint_t)N_EDGES) col_src[pos] = (int)s;
        }
    }
}

// ---------------- aggregation on bf16 y (dim 64) -> bf16 u ----------------
__global__ __launch_bounds__(256) void k_aggregate_u(const uint2* __restrict__ y2,
                                                     const int* __restrict__ row_ptr,
                                                     const int* __restrict__ col_src,
                                                     const float* __restrict__ eps, int layer,
                                                     const float* __restrict__ b1,
                                                     uint2* __restrict__ u2) {
    int wid = threadIdx.x >> 6, lane = threadIdx.x & 63;
    int gid = lane >> 4, l4 = lane & 15;
    int node = blockIdx.x * 4 + wid;
    if (node >= N_NODES) return;
    float one_eps = 1.0f + eps[layer];
    int e0 = row_ptr[node], e1 = row_ptr[node + 1];
    if (e0 < 0) e0 = 0;
    if (e1 > N_EDGES) e1 = N_EDGES;
    if (e1 < e0) e1 = e0;
    int len = e1 - e0;
    int main_end = e0 + (len & ~15);

    float4 acc[4];
    #pragma unroll
    for (int j = 0; j < 4; ++j) acc[j] = (float4){0.f, 0.f, 0.f, 0.f};

    for (int eb = e0; eb < main_end; eb += 16) {
        #pragma unroll
        for (int j = 0; j < 4; ++j) {
            uint_t s = min((uint_t)col_src[eb + 4 * j + gid], (uint_t)(N_NODES - 1));
            uint2 w = y2[(size_t)s * 16 + l4];
            acc[j].x += lo_bf(w.x); acc[j].y += hi_bf(w.x);
            acc[j].z += lo_bf(w.y); acc[j].w += hi_bf(w.y);
        }
    }
    #pragma unroll
    for (int j = 0; j < 4; ++j) {
        int ee = main_end + 4 * j + gid;
        if (ee < e1) {
            uint_t s = min((uint_t)col_src[ee], (uint_t)(N_NODES - 1));
            uint2 w = y2[(size_t)s * 16 + l4];
            acc[j].x += lo_bf(w.x); acc[j].y += hi_bf(w.x);
            acc[j].z += lo_bf(w.y); acc[j].w += hi_bf(w.y);
        }
    }

    float4 t;
    t.x = (acc[0].x + acc[1].x) + (acc[2].x + acc[3].x);
    t.y = (acc[0].y + acc[1].y) + (acc[2].y + acc[3].y);
    t.z = (acc[0].z + acc[1].z) + (acc[2].z + acc[3].z);
    t.w = (acc[0].w + acc[1].w) + (acc[2].w + acc[3].w);
    t.x += __shfl_xor(t.x, 16, 64); t.x += __shfl_xor(t.x, 32, 64);
    t.y += __shfl_xor(t.y, 16, 64); t.y += __shfl_xor(t.y, 32, 64);
    t.z += __shfl_xor(t.z, 16, 64); t.z += __shfl_xor(t.z, 32, 64);
    t.w += __shfl_xor(t.w, 16, 64); t.w += __shfl_xor(t.w, 32, 64);

    if (gid == 0) {
        uint2 ws = y2[(size_t)node * 16 + l4];
        float4 bb = *(const float4*)&b1[4 * l4];
        float ox = t.x + one_eps * lo_bf(ws.x) + bb.x;
        float oy = t.y + one_eps * hi_bf(ws.x) + bb.y;
        float oz = t.z + one_eps * lo_bf(ws.y) + bb.z;
        float ow = t.w + one_eps * hi_bf(ws.y) + bb.w;
        uint2 o2;
        o2.x = pack2(ox, oy);
        o2.y = pack2(oz, ow);
        u2[(size_t)node * 16 + l4] = o2;
    }
}

// ---------------- GEMM1 (layer 0 only): ybf = bf16(x @ W1_0) ----------------
template <int K>
__global__ __launch_bounds__(256) void k_gemm1(const float* __restrict__ A,
                                               const float* __restrict__ W,
                                               ushort_t* __restrict__ out) {
    constexpr int KP = K + 4;
    constexpr int KQ = K / 4;
    __shared__ float Al[64 * KP];
    __shared__ float Wl[K * 64];
    int tid = threadIdx.x;
    int base = blockIdx.x * 64;

    for (int i = tid; i < K * 16; i += 256)
        ((float4*)Wl)[i] = ((const float4*)W)[i];

    if (base + 64 <= N_NODES) {
        const float4* Ag = (const float4*)(A + (size_t)base * K);
        for (int i = tid; i < 16 * K; i += 256) {
            int row = i / KQ, kk = (i % KQ) * 4;
            float4 v = Ag[i];
            *(float4*)&Al[row * KP + kk] = v;
        }
    } else {
        for (int i = tid; i < 16 * K; i += 256) {
            int row = i / KQ, kk = (i % KQ) * 4;
            int grow = base + row; if (grow >= N_NODES) grow = N_NODES - 1;
            float4 v = ((const float4*)(A + (size_t)grow * K))[i % KQ];
            *(float4*)&Al[row * KP + kk] = v;
        }
    }
    __syncthreads();

    int ct = (tid & 15) * 4;
    int rb = (tid >> 4) * 4;
    float4 acc0 = {0.f, 0.f, 0.f, 0.f}, acc1 = acc0, acc2 = acc0, acc3 = acc0;
    const float* A0 = &Al[(rb + 0) * KP];
    const float* A1 = &Al[(rb + 1) * KP];
    const float* A2 = &Al[(rb + 2) * KP];
    const float* A3 = &Al[(rb + 3) * KP];
    #pragma unroll 4
    for (int k = 0; k < K; ++k) {
        float4 w = *(const float4*)&Wl[k * 64 + ct];
        float a0 = A0[k], a1 = A1[k], a2 = A2[k], a3 = A3[k];
        acc0.x = fmaf(a0, w.x, acc0.x); acc0.y = fmaf(a0, w.y, acc0.y);
        acc0.z = fmaf(a0, w.z, acc0.z); acc0.w = fmaf(a0, w.w, acc0.w);
        acc1.x = fmaf(a1, w.x, acc1.x); acc1.y = fmaf(a1, w.y, acc1.y);
        acc1.z = fmaf(a1, w.z, acc1.z); acc1.w = fmaf(a1, w.w, acc1.w);
        acc2.x = fmaf(a2, w.x, acc2.x); acc2.y = fmaf(a2, w.y, acc2.y);
        acc2.z = fmaf(a2, w.z, acc2.z); acc2.w = fmaf(a2, w.w, acc2.w);
        acc3.x = fmaf(a3, w.x, acc3.x); acc3.y = fmaf(a3, w.y, acc3.y);
        acc3.z = fmaf(a3, w.z, acc3.z); acc3.w = fmaf(a3, w.w, acc3.w);
    }

    float4 accs[4] = {acc0, acc1, acc2, acc3};
    #pragma unroll
    for (int r = 0; r < 4; ++r) {
        int row = base + rb + r;
        if (row < N_NODES) {
            ushort4 o;
            o.x = f2bf(accs[r].x); o.y = f2bf(accs[r].y);
            o.z = f2bf(accs[r].z); o.w = f2bf(accs[r].w);
            *(ushort4*)&out[(size_t)row * 64 + ct] = o;
        }
    }
}

// ---------------- fused layer tail (bf16 u input) ----------------
template <bool NEXT>
__global__ __launch_bounds__(256) void k_fused(const uint2* __restrict__ U2,
                                               const float* __restrict__ W2,
                                               const float* __restrict__ sums,
                                               const float* __restrict__ g_,
                                               const float* __restrict__ be,
                                               const float* __restrict__ b2,
                                               const int* __restrict__ batch,
                                               float* __restrict__ pooled, int layer,
                                               const float* __restrict__ W1n,
                                               ushort_t* __restrict__ ynext) {
    constexpr int K = 64, KP = 68, KQ = 16;
    __shared__ float Al[64 * KP];
    __shared__ float Wl[K * 64];
    __shared__ float W1l[NEXT ? K * 64 : 4];
    __shared__ float Pl[256];
    __shared__ __align__(16) float Sc[64];
    __shared__ __align__(16) float Sh[64];
    int tid = threadIdx.x;
    int base = blockIdx.x * 64;

    if (tid < 64) {
        const float inv_n = 1.0f / N_NODES;
        float mean = sums[tid] * inv_n;
        float var = sums[64 + tid] * inv_n - mean * mean;
        if (var < 0.f) var = 0.f;
        float inv = rsqrtf(var + 1e-5f);
        float sc = inv * g_[tid];
        Sc[tid] = sc;
        Sh[tid] = be[tid] - mean * sc;
    }
    for (int i = tid; i < K * 16; i += 256)
        ((float4*)Wl)[i] = ((const float4*)W2)[i];
    if (NEXT) {
        for (int i = tid; i < K * 16; i += 256)
            ((float4*)W1l)[i] = ((const float4*)W1n)[i];
    }
    __syncthreads();

    {
        bool full = (base + 64 <= N_NODES);
        for (int i = tid; i < 16 * K; i += 256) {
            int row = i / KQ, kq = i % KQ, kk = kq * 4;
            int grow = base + row;
            if (!full && grow >= N_NODES) grow = N_NODES - 1;
            uint2 w = U2[(size_t)grow * 16 + kq];
            float4 v = {lo_bf(w.x), hi_bf(w.x), lo_bf(w.y), hi_bf(w.y)};
            float4 sc = *(const float4*)&Sc[kk];
            float4 sh = *(const float4*)&Sh[kk];
            v.x = fmaxf(fmaf(v.x, sc.x, sh.x), 0.f);
            v.y = fmaxf(fmaf(v.y, sc.y, sh.y), 0.f);
            v.z = fmaxf(fmaf(v.z, sc.z, sh.z), 0.f);
            v.w = fmaxf(fmaf(v.w, sc.w, sh.w), 0.f);
            *(float4*)&Al[row * KP + kk] = v;
        }
    }
    __syncthreads();

    int ct = (tid & 15) * 4;
    int rb = (tid >> 4) * 4;
    float4 acc0 = {0.f, 0.f, 0.f, 0.f}, acc1 = acc0, acc2 = acc0, acc3 = acc0;
    {
        const float* A0 = &Al[(rb + 0) * KP];
        const float* A1 = &Al[(rb + 1) * KP];
        const float* A2 = &Al[(rb + 2) * KP];
        const float* A3 = &Al[(rb + 3) * KP];
        #pragma unroll 4
        for (int k = 0; k < K; ++k) {
            float4 w = *(const float4*)&Wl[k * 64 + ct];
            float a0 = A0[k], a1 = A1[k], a2 = A2[k], a3 = A3[k];
            acc0.x = fmaf(a0, w.x, acc0.x); acc0.y = fmaf(a0, w.y, acc0.y);
            acc0.z = fmaf(a0, w.z, acc0.z); acc0.w = fmaf(a0, w.w, acc0.w);
            acc1.x = fmaf(a1, w.x, acc1.x); acc1.y = fmaf(a1, w.y, acc1.y);
            acc1.z = fmaf(a1, w.z, acc1.z); acc1.w = fmaf(a1, w.w, acc1.w);
            acc2.x = fmaf(a2, w.x, acc2.x); acc2.y = fmaf(a2, w.y, acc2.y);
            acc2.z = fmaf(a2, w.z, acc2.z); acc2.w = fmaf(a2, w.w, acc2.w);
            acc3.x = fmaf(a3, w.x, acc3.x); acc3.y = fmaf(a3, w.y, acc3.y);
            acc3.z = fmaf(a3, w.z, acc3.z); acc3.w = fmaf(a3, w.w, acc3.w);
        }
    }
    __syncthreads();   // done reading Al (u); reuse it for h

    {
        float4 bb = *(const float4*)&b2[ct];
        float4 accs[4] = {acc0, acc1, acc2, acc3};
        #pragma unroll
        for (int r = 0; r < 4; ++r) {
            float4 o;
            o.x = fmaxf(accs[r].x + bb.x, 0.f);
            o.y = fmaxf(accs[r].y + bb.y, 0.f);
            o.z = fmaxf(accs[r].z + bb.z, 0.f);
            o.w = fmaxf(accs[r].w + bb.w, 0.f);
            *(float4*)&Al[(rb + r) * KP + ct] = o;
        }
    }
    __syncthreads();   // h tile ready in Al

    // ---- pooling over graph segments (batch sorted) ----
    {
        int lastEx = base + 64; if (lastEx > N_NODES) lastEx = N_NODES;
        int gstart = batch[base];
        int gend = batch[lastEx - 1];
        if (gstart < 0) gstart = 0;
        if (gend > N_GRAPHS - 1) gend = N_GRAPHS - 1;
        int col = tid & 63, q = tid >> 6;
        int rs = base;
        for (int g = gstart; g <= gend; ++g) {
            int lo = rs, hi = lastEx;
            while (lo < hi) { int mid = (lo + hi) >> 1; if (batch[mid] <= g) lo = mid + 1; else hi = mid; }
            int re = lo;
            float s = 0.f;
            for (int r = rs + q; r < re; r += 4) s += Al[(r - base) * KP + col];
            Pl[tid] = s;
            __syncthreads();
            if (tid < 64) {
                float tot = (Pl[col] + Pl[64 + col]) + (Pl[128 + col] + Pl[192 + col]);
                atomicAdd(&pooled[g * 256 + layer * 64 + col], tot);
            }
            __syncthreads();
            rs = re;
        }
    }

    // ---- second GEMM: ynext = bf16( h @ W1n ) ----
    if (NEXT) {
        float4 y0 = {0.f, 0.f, 0.f, 0.f}, y1 = y0, y2_ = y0, y3 = y0;
        const float* A0 = &Al[(rb + 0) * KP];
        const float* A1 = &Al[(rb + 1) * KP];
        const float* A2 = &Al[(rb + 2) * KP];
        const float* A3 = &Al[(rb + 3) * KP];
        #pragma unroll 4
        for (int k = 0; k < K; ++k) {
            float4 w = *(const float4*)&W1l[k * 64 + ct];
            float a0 = A0[k], a1 = A1[k], a2 = A2[k], a3 = A3[k];
            y0.x = fmaf(a0, w.x, y0.x); y0.y = fmaf(a0, w.y, y0.y);
            y0.z = fmaf(a0, w.z, y0.z); y0.w = fmaf(a0, w.w, y0.w);
            y1.x = fmaf(a1, w.x, y1.x); y1.y = fmaf(a1, w.y, y1.y);
            y1.z = fmaf(a1, w.z, y1.z); y1.w = fmaf(a1, w.w, y1.w);
            y2_.x = fmaf(a2, w.x, y2_.x); y2_.y = fmaf(a2, w.y, y2_.y);
            y2_.z = fmaf(a2, w.z, y2_.z); y2_.w = fmaf(a2, w.w, y2_.w);
            y3.x = fmaf(a3, w.x, y3.x); y3.y = fmaf(a3, w.y, y3.y);
            y3.z = fmaf(a3, w.z, y3.z); y3.w = fmaf(a3, w.w, y3.w);
        }
        float4 ys[4] = {y0, y1, y2_, y3};
        #pragma unroll
        for (int r = 0; r < 4; ++r) {
            int row = base + rb + r;
            if (row < N_NODES) {
                ushort4 o;
                o.x = f2bf(ys[r].x); o.y = f2bf(ys[r].y);
                o.z = f2bf(ys[r].z); o.w = f2bf(ys[r].w);
                *(ushort4*)&ynext[(size_t)row * 64 + ct] = o;
            }
        }
    }
}

// ---------------- column stats over bf16 u [N_NODES x 64] ----------------
__global__ __launch_bounds__(256) void k_stats(const uint2* __restrict__ u2, float* __restrict__ sums) {
    __shared__ float sh[256 * 8];
    int tid = threadIdx.x;
    float a[4] = {0.f, 0.f, 0.f, 0.f}, b[4] = {0.f, 0.f, 0.f, 0.f};
    for (size_t i = (size_t)blockIdx.x * 256 + tid; i < (size_t)N_NODES * 16; i += (size_t)gridDim.x * 256) {
        uint2 w = u2[i];
        float v0 = lo_bf(w.x), v1 = hi_bf(w.x), v2 = lo_bf(w.y), v3 = hi_bf(w.y);
        a[0] += v0; b[0] += v0 * v0;
        a[1] += v1; b[1] += v1 * v1;
        a[2] += v2; b[2] += v2 * v2;
        a[3] += v3; b[3] += v3 * v3;
    }
    #pragma unroll
    for (int j = 0; j < 4; ++j) { sh[tid * 8 + j] = a[j]; sh[tid * 8 + 4 + j] = b[j]; }
    __syncthreads();
    if (tid < 64) {
        int quad = tid >> 2, o = tid & 3;
        float s = 0.f, ss = 0.f;
        for (int g = 0; g < 16; ++g) {
            int t = g * 16 + quad;
            s  += sh[t * 8 + o];
            ss += sh[t * 8 + 4 + o];
        }
        atomicAdd(&sums[tid], s);
        atomicAdd(&sums[64 + tid], ss);
    }
}

// ---------------- head ----------------
__global__ __launch_bounds__(64) void k_head1(const float* __restrict__ pooled,
                                              const float* __restrict__ W, const float* __restrict__ b,
                                              float* __restrict__ t1) {
    __shared__ __align__(16) float pl[256];
    int g = blockIdx.x, lane = threadIdx.x;
    ((float4*)pl)[lane] = ((const float4*)(pooled + g * 256))[lane];
    __syncthreads();
    float acc = b[lane];
    for (int k = 0; k < 256; ++k) acc += pl[k] * W[k * 64 + lane];
    t1[g * 64 + lane] = acc;
}

__global__ __launch_bounds__(64) void k_head3(const float* __restrict__ t1,
                                              const float* __restrict__ g_, const float* __restrict__ b_,
                                              const float* __restrict__ W2, const float* __restrict__ b2,
                                              float* __restrict__ out) {
    __shared__ float v[64];
    __shared__ float o[16];
    int g = blockIdx.x, lane = threadIdx.x;
    float s = 0.f, q = 0.f;
    for (int r = 0; r < N_GRAPHS; ++r) {
        float vv = t1[r * 64 + lane];
        s += vv; q += vv * vv;
    }
    float mean = s * (1.0f / N_GRAPHS);
    float var = q * (1.0f / N_GRAPHS) - mean * mean;
    if (var < 0.f) var = 0.f;
    float inv = rsqrtf(var + 1e-5f);
    float sc = inv * g_[lane];
    float sh = b_[lane] - mean * sc;
    float x = t1[g * 64 + lane] * sc + sh;
    v[lane] = fmaxf(x, 0.f);
    __syncthreads();
    if (lane < N_CLASSES) {
        float acc = b2[lane];
        for (int k = 0; k < 64; ++k) acc += v[k] * W2[k * N_CLASSES + lane];
        o[lane] = acc;
    }
    __syncthreads();
    if (lane < N_CLASSES) {
        float m = -1e30f;
        for (int k = 0; k < N_CLASSES; ++k) m = fmaxf(m, o[k]);
        float ssum = 0.f;
        for (int k = 0; k < N_CLASSES; ++k) ssum += expf(o[k] - m);
        out[g * N_CLASSES + lane] = o[lane] - m - logf(ssum);
    }
}

// ---------------- launch ----------------
extern "C" void kernel_launch(void* const* d_in, const int* in_sizes, int n_in,
                              void* d_out, int out_size, void* d_ws, size_t ws_size,
                              hipStream_t stream) {
    const float* x      = (const float*)d_in[0];
    const int*   ei     = (const int*)d_in[1];
    const int*   srcArr = ei;
    const int*   dstArr = ei + N_EDGES;
    const int*   batch  = (const int*)d_in[2];
    const float* eps    = (const float*)d_in[3];
    const float* W1_0   = (const float*)d_in[4];
    const float* b1_0   = (const float*)d_in[5];
    const float* g_0    = (const float*)d_in[6];
    const float* be_0   = (const float*)d_in[7];
    const float* W2_0   = (const float*)d_in[8];
    const float* b2_0   = (const float*)d_in[9];
    const float* W1_r   = (const float*)d_in[10];
    const float* b1_r   = (const float*)d_in[11];
    const float* g_r    = (const float*)d_in[12];
    const float* be_r   = (const float*)d_in[13];
    const float* W2_r   = (const float*)d_in[14];
    const float* b2_r   = (const float*)d_in[15];
    const float* lin1W  = (const float*)d_in[16];
    const float* lin1b  = (const float*)d_in[17];
    const float* bn_g   = (const float*)d_in[18];
    const float* bn_b   = (const float*)d_in[19];
    const float* lin2W  = (const float*)d_in[20];
    const float* lin2b  = (const float*)d_in[21];

    char* ws = (char*)d_ws;
    auto alloc = [&](size_t bytes) {
        char* p = ws;
        ws += (bytes + 255) & ~(size_t)255;
        return p;
    };
    int*      deg     = (int*)alloc((size_t)N_NODES * 4);
    int*      row_ptr = (int*)alloc(((size_t)N_NODES + 1) * 4);
    ushort_t* rank    = (ushort_t*)alloc((size_t)N_EDGES * 2);
    int*      bsum    = (int*)alloc((size_t)N_TILES * 4);
    int*      boff    = (int*)alloc(((size_t)N_TILES + 1) * 4);
    int*      col_src = (int*)alloc((size_t)N_EDGES * 4);
    ushort_t* ybf     = (ushort_t*)alloc((size_t)N_NODES * 64 * 2);
    ushort_t* ubf     = (ushort_t*)alloc((size_t)N_NODES * 64 * 2);
    float*    statsA  = (float*)alloc(NLAYERS * 128 * 4);
    float*    pooled  = (float*)alloc((size_t)N_GRAPHS * 256 * 4);
    float*    t1      = (float*)alloc((size_t)N_GRAPHS * 64 * 4);

    const int e4_grid = (N_EDGES + 1023) / 1024;
    k_zero<<<(N_GRAPHS * 256 + 255) / 256, 256, 0, stream>>>(deg, statsA, pooled);
    k_degree_rank<<<e4_grid, 256, 0, stream>>>(dstArr, deg, rank);
    k_tilesum<<<N_TILES, 256, 0, stream>>>(deg, bsum);
    k_tilescan<<<1, 512, 0, stream>>>(bsum, boff);
    k_tileapply<<<N_TILES, 256, 0, stream>>>(deg, boff, row_ptr);
    k_fill<<<e4_grid, 256, 0, stream>>>(srcArr, dstArr, rank, row_ptr, col_src);

    const int agg_grid  = N_NODES / 4;              // 25000, exact
    const int gemm_grid = (N_NODES + 63) / 64;      // 1563

    // layer 0 front GEMM: y0 = bf16(x @ W1_0)
    k_gemm1<128><<<gemm_grid, 256, 0, stream>>>(x, W1_0, ybf);

    for (int l = 0; l < NLAYERS; ++l) {
        const float *b1, *gg, *be, *W2, *b2;
        if (l == 0) { b1 = b1_0; gg = g_0; be = be_0; W2 = W2_0; b2 = b2_0; }
        else {
            b1 = b1_r + (size_t)(l - 1) * 64;
            gg = g_r  + (size_t)(l - 1) * 64;
            be = be_r + (size_t)(l - 1) * 64;
            W2 = W2_r + (size_t)(l - 1) * 64 * 64;
            b2 = b2_r + (size_t)(l - 1) * 64;
        }
        k_aggregate_u<<<agg_grid, 256, 0, stream>>>((const uint2*)ybf, row_ptr, col_src, eps, l, b1,
                                                    (uint2*)ubf);
        k_stats<<<512, 256, 0, stream>>>((const uint2*)ubf, statsA + l * 128);
        if (l < NLAYERS - 1) {
            const float* W1n = W1_r + (size_t)l * 64 * 64;
            k_fused<true><<<gemm_grid, 256, 0, stream>>>((const uint2*)ubf, W2, statsA + l * 128, gg, be, b2,
                                                         batch, pooled, l, W1n, ybf);
        } else {
            k_fused<false><<<gemm_grid, 256, 0, stream>>>((const uint2*)ubf, W2, statsA + l * 128, gg, be, b2,
                                                          batch, pooled, l, nullptr, nullptr);
        }
    }

    k_head1<<<N_GRAPHS, 64, 0, stream>>>(pooled, lin1W, lin1b, t1);
    k_head3<<<N_GRAPHS, 64, 0, stream>>>(t1, bn_g, bn_b, lin2W, lin2b, (float*)d_out);
}